// Round 1
// baseline (448.573 us; speedup 1.0000x reference)
//
#include <hip/hip_runtime.h>

// RetNet retention (diagonal state): per-channel linear scan over S.
// B=4, S=4096, D=2048, H=16, hd=128. fp32 in/out.
//
// Two-pass chunked scan:
//   Kernel A: per (float4-group g, chunk c) compute chunk summary
//             A[c][g] = sum_{i<L} d^(L-1-i) * k_i*v_i   (the chunk-local final state)
//   Kernel B: per (g, c) fold A[0..c-1] with d^L into carry (coalesced L2 reads),
//             then replay the exact recurrence over the chunk, out = q*r.

namespace {

constexpr int kBlk  = 256;
constexpr int kB    = 4;
constexpr int kS    = 4096;
constexpr int kD    = 2048;
constexpr int kRow  = kD / 4;        // 512 float4 per (b,s) row
constexpr int kNG   = kB * kRow;     // 2048 float4-groups (b, j4)
constexpr int kC    = 64;            // chunks over S
constexpr int kL    = kS / kC;       // 64 steps per chunk

__global__ __launch_bounds__(kBlk) void chunk_state_kernel(
    const float4* __restrict__ k, const float4* __restrict__ v,
    const float* __restrict__ decay, float4* __restrict__ A) {
  const int tid = blockIdx.x * kBlk + threadIdx.x;   // [0, kNG*kC)
  const int g   = tid & (kNG - 1);
  const int c   = tid >> 11;                          // tid / kNG
  const int b   = g >> 9;                             // g / kRow
  const int j4  = g & (kRow - 1);
  const int h   = j4 >> 5;                            // (j4*4)/128
  const float d = decay[h];

  int base = (b * kS + c * kL) * kRow + j4;           // float4 index
  float4 r = make_float4(0.f, 0.f, 0.f, 0.f);
#pragma unroll 4
  for (int i = 0; i < kL; ++i) {
    float4 kk = k[base + i * kRow];
    float4 vv = v[base + i * kRow];
    r.x = fmaf(d, r.x, kk.x * vv.x);
    r.y = fmaf(d, r.y, kk.y * vv.y);
    r.z = fmaf(d, r.z, kk.z * vv.z);
    r.w = fmaf(d, r.w, kk.w * vv.w);
  }
  A[c * kNG + g] = r;
}

__global__ __launch_bounds__(kBlk) void retention_out_kernel(
    const float4* __restrict__ q, const float4* __restrict__ k,
    const float4* __restrict__ v, const float* __restrict__ decay,
    const float4* __restrict__ A, float4* __restrict__ out) {
  const int tid = blockIdx.x * kBlk + threadIdx.x;
  const int g   = tid & (kNG - 1);
  const int c   = tid >> 11;
  const int b   = g >> 9;
  const int j4  = g & (kRow - 1);
  const int h   = j4 >> 5;
  const float d = decay[h];

  // d^L via 6 squarings (L = 64 = 2^6)
  float dL = d;
#pragma unroll
  for (int t = 0; t < 6; ++t) dL *= dL;

  // carry = state at end of chunk c-1 = scan of A[0..c-1] with factor d^L.
  // All lanes in a wave share c -> no divergence; A reads are lane-coalesced.
  float4 r = make_float4(0.f, 0.f, 0.f, 0.f);
  for (int cc = 0; cc < c; ++cc) {
    float4 a = A[cc * kNG + g];
    r.x = fmaf(dL, r.x, a.x);
    r.y = fmaf(dL, r.y, a.y);
    r.z = fmaf(dL, r.z, a.z);
    r.w = fmaf(dL, r.w, a.w);
  }

  int base = (b * kS + c * kL) * kRow + j4;
#pragma unroll 4
  for (int i = 0; i < kL; ++i) {
    float4 qq = q[base + i * kRow];
    float4 kk = k[base + i * kRow];
    float4 vv = v[base + i * kRow];
    r.x = fmaf(d, r.x, kk.x * vv.x);
    r.y = fmaf(d, r.y, kk.y * vv.y);
    r.z = fmaf(d, r.z, kk.z * vv.z);
    r.w = fmaf(d, r.w, kk.w * vv.w);
    float4 o;
    o.x = qq.x * r.x;
    o.y = qq.y * r.y;
    o.z = qq.z * r.z;
    o.w = qq.w * r.w;
    out[base + i * kRow] = o;
  }
}

}  // namespace

extern "C" void kernel_launch(void* const* d_in, const int* in_sizes, int n_in,
                              void* d_out, int out_size, void* d_ws, size_t ws_size,
                              hipStream_t stream) {
  const float4* q     = (const float4*)d_in[0];
  const float4* k     = (const float4*)d_in[1];
  const float4* v     = (const float4*)d_in[2];
  const float*  decay = (const float*)d_in[3];
  float4* out = (float4*)d_out;
  float4* A   = (float4*)d_ws;   // kC * kNG float4 = 2 MiB

  const int nthreads = kNG * kC;           // 131072
  const int nblocks  = nthreads / kBlk;    // 512

  chunk_state_kernel<<<nblocks, kBlk, 0, stream>>>(k, v, decay, A);
  retention_out_kernel<<<nblocks, kBlk, 0, stream>>>(q, k, v, decay, A, out);
}